// Round 1
// baseline (1918.918 us; speedup 1.0000x reference)
//
#include <hip/hip_runtime.h>
#include <hip/hip_bf16.h>
#include <stdint.h>

typedef __hip_bfloat16 bf16;
using frag_ab = __attribute__((ext_vector_type(8))) short;
using frag_cd = __attribute__((ext_vector_type(4))) float;

static __device__ __forceinline__ float hsig(float x){
    return fminf(fmaxf((x + 3.0f) * (1.0f/6.0f), 0.0f), 1.0f);
}
static inline int ceildiv(int a, int b){ return (a + b - 1) / b; }

// ---------------- weight conversion: w[O][256][3][3] fp32 -> bw[Opad][2304] bf16, K = k*256+c ----
__global__ __launch_bounds__(256) void k_convw(const float* __restrict__ w, bf16* __restrict__ bw,
                                               int Opad, int Ovalid){
    int i = blockIdx.x*256 + threadIdx.x;
    int total = Opad*2304;
    if (i >= total) return;
    int o = i / 2304, r = i - o*2304;
    int k = r >> 8, c = r & 255;
    float v = 0.f;
    if (o < Ovalid) v = w[((size_t)(o*256 + c))*9 + k];
    bw[i] = __float2bfloat16(v);
}

// ---------------- deformable / im2col gather: produces samp[Mc_rows][2304] bf16 ----------------
// OM layout per mid-pixel: [32] floats = {off(2k),off(2k+1) k=0..8 ; mask k=0..8 at 18+k ; pad}
__global__ __launch_bounds__(256) void k_gather(
    const float* __restrict__ X, const float* __restrict__ OM, bf16* __restrict__ S,
    int p0, int Mtot, int Ho, int Wo, int Hi, int Wi, int HmWm, int Wm, int stride, int osub)
{
    __shared__ __align__(16) int   mi[64][4];
    __shared__ __align__(16) float mw[64][4];
    __shared__ bf16 T[256*64];
    const int t = threadIdx.x;
    const int HoWo = Ho*Wo;
    const int HiWi = Hi*Wi;
    const int pbase = p0 + blockIdx.x*64;
    const int pl = t & 63;
    const int c0 = (t >> 6) << 6;

    for (int k = 0; k < 9; ++k){
        if (t < 64){
            int p = pbase + t;
            bool pv = (p < Mtot);
            int pp = pv ? p : 0;
            int b = pp / HoWo; int r = pp - b*HoWo; int y = r / Wo; int x = r - y*Wo;
            float offy = 0.f, offx = 0.f, mk = 1.f;
            if (OM){
                size_t ob = ((size_t)b*HmWm + (size_t)(y*osub)*Wm + (size_t)(x*osub)) * 32;
                offy = OM[ob + 2*k]; offx = OM[ob + 2*k + 1]; mk = OM[ob + 18 + k];
            }
            if (!pv) mk = 0.f;
            int kh = k/3, kw = k - kh*3;
            float py = (float)(y*stride - 1 + kh) + offy;
            float px = (float)(x*stride - 1 + kw) + offx;
            float y0f = floorf(py), x0f = floorf(px);
            float ly = py - y0f, lx = px - x0f;
            int y0 = (int)y0f, x0 = (int)x0f;
            int y1 = y0 + 1, x1 = x0 + 1;
            float vy0 = (y0 >= 0 && y0 < Hi) ? 1.f : 0.f;
            float vy1 = (y1 >= 0 && y1 < Hi) ? 1.f : 0.f;
            float vx0 = (x0 >= 0 && x0 < Wi) ? 1.f : 0.f;
            float vx1 = (x1 >= 0 && x1 < Wi) ? 1.f : 0.f;
            float w00 = (1.f-ly)*(1.f-lx)*mk*vy0*vx0;
            float w01 = (1.f-ly)*lx*mk*vy0*vx1;
            float w10 = ly*(1.f-lx)*mk*vy1*vx0;
            float w11 = ly*lx*mk*vy1*vx1;
            int y0c = min(max(y0,0),Hi-1), y1c = min(max(y1,0),Hi-1);
            int x0c = min(max(x0,0),Wi-1), x1c = min(max(x1,0),Wi-1);
            int base = b*256*HiWi;
            mi[t][0] = base + y0c*Wi + x0c;
            mi[t][1] = base + y0c*Wi + x1c;
            mi[t][2] = base + y1c*Wi + x0c;
            mi[t][3] = base + y1c*Wi + x1c;
            mw[t][0] = w00; mw[t][1] = w01; mw[t][2] = w10; mw[t][3] = w11;
        }
        __syncthreads();
        int4  ii = *(const int4*)mi[pl];
        float4 ww = *(const float4*)mw[pl];
        #pragma unroll 4
        for (int j = 0; j < 64; ++j){
            int c = c0 + j;
            const float* xp = X + (size_t)c * HiWi;
            float v = ww.x*xp[ii.x] + ww.y*xp[ii.y] + ww.z*xp[ii.z] + ww.w*xp[ii.w];
            T[c*64 + (pl ^ ((c & 31) << 1))] = __float2bfloat16(v);
        }
        __syncthreads();
        size_t rowbase = (size_t)(blockIdx.x*64) * 2304 + (size_t)k*256 + t;
        #pragma unroll 4
        for (int i = 0; i < 64; ++i){
            S[rowbase + (size_t)i*2304] = T[t*64 + (i ^ ((t & 31) << 1))];
        }
        __syncthreads();
    }
}

// ---------------- NT GEMM: C[M][ldc] = A[Mpad][2304] * Bw[Npad][2304]^T (+bias), bf16 MFMA ------
__global__ __launch_bounds__(256) void k_gemm(
    const bf16* __restrict__ A, const bf16* __restrict__ Bw,
    float* __restrict__ C, const float* __restrict__ bias,
    int M, int ldc, int Nvalid, int nbn)
{
    __shared__ __align__(16) bf16 sA[128*64];
    __shared__ __align__(16) bf16 sB[128*64];
    const int t = threadIdx.x;
    const int mb = blockIdx.x / nbn;
    const int nb = blockIdx.x - mb*nbn;
    const int m0 = mb*128, n0 = nb*128;
    const int w = t >> 6, l = t & 63;
    const int wr = w >> 1, wc = w & 1;
    const int lr = l & 15, lk = (l >> 4) * 8;
    const int K = 2304;
    frag_cd acc[4][4];
    frag_cd zero = {0.f, 0.f, 0.f, 0.f};
    for (int i = 0; i < 4; ++i) for (int j = 0; j < 4; ++j) acc[i][j] = zero;

    for (int kt = 0; kt < 36; ++kt){
        int k0 = kt*64;
        __syncthreads();
        #pragma unroll
        for (int i = 0; i < 4; ++i){
            int f = i*256 + t;
            int row = f >> 3, kc = (f & 7) << 3;
            *(int4*)&sA[row*64 + kc] = *(const int4*)&A[(size_t)(m0 + row)*K + (k0 + kc)];
            *(int4*)&sB[row*64 + kc] = *(const int4*)&Bw[(size_t)(n0 + row)*K + (k0 + kc)];
        }
        __syncthreads();
        #pragma unroll
        for (int kk = 0; kk < 2; ++kk){
            frag_ab av[4], bv[4];
            #pragma unroll
            for (int i = 0; i < 4; ++i){
                av[i] = *(const frag_ab*)&sA[(wr*64 + i*16 + lr)*64 + kk*32 + lk];
                bv[i] = *(const frag_ab*)&sB[(wc*64 + i*16 + lr)*64 + kk*32 + lk];
            }
            #pragma unroll
            for (int mi_ = 0; mi_ < 4; ++mi_)
                #pragma unroll
                for (int ni = 0; ni < 4; ++ni)
                    acc[mi_][ni] = __builtin_amdgcn_mfma_f32_16x16x32_bf16(av[mi_], bv[ni], acc[mi_][ni], 0, 0, 0);
        }
    }
    #pragma unroll
    for (int mi_ = 0; mi_ < 4; ++mi_){
        int gr0 = m0 + wr*64 + mi_*16 + ((l >> 4) << 2);
        #pragma unroll
        for (int ni = 0; ni < 4; ++ni){
            int gc = n0 + wc*64 + ni*16 + lr;
            if (gc < Nvalid){
                float bv_ = bias ? bias[gc] : 0.f;
                #pragma unroll
                for (int j = 0; j < 4; ++j){
                    int r = gr0 + j;
                    if (r < M) C[(size_t)r*ldc + gc] = acc[mi_][ni][j] + bv_;
                }
            }
        }
    }
}

// ---------------- sigmoid on mask channels of om (in place) ----------------
__global__ __launch_bounds__(256) void k_omsig(float* __restrict__ om, int M){
    int i = blockIdx.x*256 + threadIdx.x;
    if (i >= M*9) return;
    int p = i / 9, ch = 18 + (i - p*9);
    float v = om[(size_t)p*32 + ch];
    om[(size_t)p*32 + ch] = 1.f / (1.f + expf(-v));
}

// ---------------- per-(b,c) partial sums over HW (NHWC input) ----------------
__global__ __launch_bounds__(256) void k_reduce(const float* __restrict__ F, float* __restrict__ part,
                                                int HW, int nchunk){
    int b = blockIdx.x / nchunk;
    int ch = blockIdx.x - b*nchunk;
    int R = (HW + nchunk - 1) / nchunk;
    int rbeg = ch*R, rend = min(rbeg + R, HW);
    int t = threadIdx.x;
    float s1 = 0.f, s2 = 0.f;
    for (int r = rbeg; r < rend; ++r){
        float v = F[((size_t)b*HW + r)*256 + t];
        s1 += v; s2 += v*v;
    }
    size_t o = ((size_t)blockIdx.x*256 + t) * 2;
    part[o] = s1; part[o+1] = s2;
}

// ---------------- finalize GN stats + normalized GAP (mode0) or plain GAP (mode1) ---------------
__global__ __launch_bounds__(256) void k_stats(const float* __restrict__ part, int nchunk, int HW,
    const float* __restrict__ gamma, const float* __restrict__ beta,
    float* __restrict__ stats, float* __restrict__ gapn, int mode)
{
    int b = blockIdx.x, t = threadIdx.x;
    float s1 = 0.f, s2 = 0.f;
    for (int j = 0; j < nchunk; ++j){
        size_t o = ((size_t)(b*nchunk + j)*256 + t) * 2;
        s1 += part[o]; s2 += part[o+1];
    }
    float invHW = 1.0f / (float)HW;
    if (mode == 1){ gapn[b*256 + t] = s1*invHW; return; }
    float g1 = s1, g2 = s2;
    #pragma unroll
    for (int m = 8; m >= 1; m >>= 1){ g1 += __shfl_xor(g1, m, 16); g2 += __shfl_xor(g2, m, 16); }
    float mu  = g1 * invHW * (1.f/16.f);
    float var = g2 * invHW * (1.f/16.f) - mu*mu;
    float rstd = rsqrtf(var + 1e-5f);
    if ((t & 15) == 0){ int g = t >> 4; stats[(b*16+g)*2] = mu; stats[(b*16+g)*2+1] = rstd; }
    gapn[b*256 + t] = (s1*invHW - mu)*rstd*gamma[t] + beta[t];
}

// ---------------- bilinear align-corners resize of normalized high feature (NHWC) ----------------
__global__ __launch_bounds__(256) void k_resize(const float* __restrict__ Fs, float* __restrict__ Fr,
    const float* __restrict__ stats, const float* __restrict__ gamma, const float* __restrict__ beta,
    int Hm, int Wm, int Hh, int Wh)
{
    int t = threadIdx.x;
    int HWm = Hm*Wm, HWh = Hh*Wh;
    int Mm = 2*HWm;
    for (int i = 0; i < 8; ++i){
        int po = blockIdx.x*8 + i;
        if (po >= Mm) break;
        int b = po / HWm; int r = po - b*HWm; int y = r / Wm; int x = r - y*Wm;
        int ny = y*(Hh-1); int y0 = ny/(Hm-1); float wy = (float)(ny - y0*(Hm-1)) / (float)(Hm-1);
        int y1 = min(y0+1, Hh-1);
        int nx = x*(Wh-1); int x0 = nx/(Wm-1); float wx = (float)(nx - x0*(Wm-1)) / (float)(Wm-1);
        int x1 = min(x0+1, Wh-1);
        size_t basep = (size_t)b*HWh;
        float v00 = Fs[(basep + y0*Wh + x0)*256 + t];
        float v01 = Fs[(basep + y0*Wh + x1)*256 + t];
        float v10 = Fs[(basep + y1*Wh + x0)*256 + t];
        float v11 = Fs[(basep + y1*Wh + x1)*256 + t];
        float v = (1.f-wy)*((1.f-wx)*v00 + wx*v01) + wy*((1.f-wx)*v10 + wx*v11);
        int g = t >> 4;
        float mu = stats[(b*16+g)*2], rs = stats[(b*16+g)*2+1];
        Fr[(size_t)po*256 + t] = (v - mu)*rs*gamma[t] + beta[t];
    }
}

// ---------------- attention scalars + dyrelu coefficients (per batch) ----------------
__global__ __launch_bounds__(256) void k_attn(const float* __restrict__ gapn,
    const float* __restrict__ sw, const float* __restrict__ sb,
    const float* __restrict__ w1, const float* __restrict__ b1v,
    const float* __restrict__ w2, const float* __restrict__ b2v,
    float* __restrict__ abr, float* __restrict__ dyc, int nbr)
{
    int b = blockIdx.x, t = threadIdx.x;
    const int B = gridDim.x;
    __shared__ float red[256];
    __shared__ float asl[3];
    __shared__ float gm[256];
    __shared__ float hh[64];
    for (int br = 0; br < nbr; ++br){
        red[t] = gapn[((size_t)br*B + b)*256 + t] * sw[t];
        __syncthreads();
        for (int s = 128; s > 0; s >>= 1){ if (t < s) red[t] += red[t+s]; __syncthreads(); }
        if (t == 0) asl[br] = hsig(fmaxf(red[0] + sb[0], 0.f));
        __syncthreads();
    }
    float gmv = 0.f;
    for (int br = 0; br < nbr; ++br) gmv += asl[br]*gapn[((size_t)br*B + b)*256 + t];
    gmv /= (float)nbr;
    gm[t] = gmv;
    __syncthreads();
    if (t < 64){
        float h = b1v[t];
        for (int c = 0; c < 256; ++c) h += w1[t*256 + c]*gm[c];
        hh[t] = fmaxf(h, 0.f);
    }
    __syncthreads();
    float co[4];
    #pragma unroll
    for (int q = 0; q < 4; ++q){
        int o = q*256 + t;
        float s = b2v[o];
        for (int kk = 0; kk < 64; ++kk) s += w2[o*64 + kk]*hh[kk];
        co[q] = hsig(s);
    }
    dyc[((size_t)b*256 + t)*4 + 0] = (co[0] - 0.5f)*2.f + 1.f;
    dyc[((size_t)b*256 + t)*4 + 1] =  co[1] - 0.5f;
    dyc[((size_t)b*256 + t)*4 + 2] = (co[2] - 0.5f)*2.f;
    dyc[((size_t)b*256 + t)*4 + 3] =  co[3] - 0.5f;
    if (t < nbr) abr[b*3 + t] = asl[t];
}

// ---------------- combine branches + dyrelu, NHWC -> NCHW output ----------------
__global__ __launch_bounds__(256) void k_combine(
    const float* __restrict__ f0, const float* __restrict__ f1, const float* __restrict__ f2n,
    const float* __restrict__ stats,
    const float* __restrict__ g0, const float* __restrict__ b0,
    const float* __restrict__ gl, const float* __restrict__ bl,
    const float* __restrict__ abr, const float* __restrict__ dyc,
    float* __restrict__ outp, int H, int W, int nbr)
{
    __shared__ float TL[256*17];
    int t = threadIdx.x;
    int nchx = (W + 15) >> 4;
    int bid = blockIdx.x;
    int cx = bid % nchx; int rem = bid / nchx;
    int y = rem % H; int b = rem / H;
    float a0 = abr[b*3 + 0];
    float alow = f1 ? abr[b*3 + 1] : 0.f;
    float ahigh = abr[b*3 + (nbr-1)];
    float inv = 1.f / (float)nbr;
    int g = t >> 4;
    float mu0 = stats[b*32 + g*2],       rs0 = stats[b*32 + g*2 + 1];
    float mu1 = f1 ? stats[64 + b*32 + g*2] : 0.f;
    float rs1 = f1 ? stats[64 + b*32 + g*2 + 1] : 0.f;
    float4 dc = *(const float4*)&dyc[((size_t)b*256 + t)*4];
    size_t HW = (size_t)H*W;
    for (int i = 0; i < 16; ++i){
        int x = (cx << 4) + i;
        if (x < W){
            size_t row = (size_t)b*HW + (size_t)y*W + x;
            float v = a0 * ((f0[row*256 + t] - mu0)*rs0*g0[t] + b0[t]);
            if (f1)  v += alow  * ((f1[row*256 + t] - mu1)*rs1*gl[t] + bl[t]);
            if (f2n) v += ahigh * f2n[row*256 + t];
            v *= inv;
            TL[t*17 + i] = fmaxf(v*dc.x + dc.y, v*dc.z + dc.w);
        }
    }
    __syncthreads();
    int px = t & 15, cw = t >> 4;
    for (int cb = 0; cb < 16; ++cb){
        int c = cb*16 + cw;
        int x = (cx << 4) + px;
        if (x < W) outp[((size_t)(b*256 + c)*H + y)*W + x] = TL[c*17 + px];
    }
}

extern "C" void kernel_launch(void* const* d_in, const int* in_sizes, int n_in,
                              void* d_out, int out_size, void* d_ws, size_t ws_size,
                              hipStream_t stream)
{
    (void)in_sizes; (void)n_in; (void)out_size;
    const float* X[3]   = {(const float*)d_in[0], (const float*)d_in[1], (const float*)d_in[2]};
    const float* off_w  = (const float*)d_in[3];
    const float* off_b  = (const float*)d_in[4];
    const float* wbr[3] = {(const float*)d_in[5], (const float*)d_in[8], (const float*)d_in[11]};
    const float* gbr[3] = {(const float*)d_in[6], (const float*)d_in[9], (const float*)d_in[12]};
    const float* bbr[3] = {(const float*)d_in[7], (const float*)d_in[10], (const float*)d_in[13]};
    const float* sw  = (const float*)d_in[14];
    const float* sb  = (const float*)d_in[15];
    const float* d1w = (const float*)d_in[16];
    const float* d1b = (const float*)d_in[17];
    const float* d2w = (const float*)d_in[18];
    const float* d2b = (const float*)d_in[19];

    const int Hs[3] = {80, 40, 20};
    uint8_t* base = (uint8_t*)d_ws;
    size_t off = 0;
    auto alloc = [&](size_t bytes)->void*{
        off = (off + 255) & ~(size_t)255;
        void* p = base + off; off += bytes; return p;
    };
    bf16* BWO = (bf16*)alloc((size_t)128*2304*2);
    bf16* BWB[3];
    for (int i = 0; i < 3; ++i) BWB[i] = (bf16*)alloc((size_t)256*2304*2);
    float* OM   = (float*)alloc((size_t)12800*32*4);
    float* F0   = (float*)alloc((size_t)12800*256*4);
    float* F1   = (float*)alloc((size_t)3200*256*4);
    float* F2s  = (float*)alloc((size_t)3200*256*4);
    float* F2r  = (float*)alloc((size_t)12800*256*4);
    float* PART = (float*)alloc((size_t)2*32*256*2*4);
    float* GAPN = (float*)alloc((size_t)3*2*256*4);
    float* STATS= (float*)alloc((size_t)3*2*16*2*4);
    float* ABR  = (float*)alloc((size_t)2*3*4 + 32);
    float* DYC  = (float*)alloc((size_t)2*256*4*4);
    off = (off + 255) & ~(size_t)255;
    size_t remain = (ws_size > off) ? ws_size - off : 0;
    int cap = (int)(remain / 4608);
    cap &= ~127;
    if (cap > 12800) cap = 12800;
    if (cap < 128) cap = 128;
    bf16* SAMP = (bf16*)(base + off);

    k_convw<<<ceildiv(128*2304,256),256,0,stream>>>(off_w, BWO, 128, 27);
    for (int i = 0; i < 3; ++i)
        k_convw<<<ceildiv(256*2304,256),256,0,stream>>>(wbr[i], BWB[i], 256, 256);

    size_t lvl_off = 0;
    for (int L = 0; L < 3; ++L){
        int H = Hs[L], W = Hs[L];
        int HW = H*W, M = 2*HW;
        bool has_low = (L > 0), has_high = (L < 2);
        int nbr = 1 + (has_low ? 1 : 0) + (has_high ? 1 : 0);
        int slotH = nbr - 1;

        // offset conv (im2col + GEMM N=27) -> OM, then sigmoid masks
        for (int p0 = 0; p0 < M; p0 += cap){
            int Mc = min(cap, M - p0);
            k_gather<<<ceildiv(Mc,64),256,0,stream>>>(X[L], nullptr, SAMP, p0, M, H, W, H, W, HW, W, 1, 1);
            k_gemm<<<ceildiv(Mc,128)*1,256,0,stream>>>(SAMP, BWO, OM + (size_t)p0*32, off_b, Mc, 32, 27, 1);
        }
        k_omsig<<<ceildiv(M*9,256),256,0,stream>>>(OM, M);

        // mid branch (slot 0)
        for (int p0 = 0; p0 < M; p0 += cap){
            int Mc = min(cap, M - p0);
            k_gather<<<ceildiv(Mc,64),256,0,stream>>>(X[L], OM, SAMP, p0, M, H, W, H, W, HW, W, 1, 1);
            k_gemm<<<ceildiv(Mc,128)*2,256,0,stream>>>(SAMP, BWB[0], F0 + (size_t)p0*256, nullptr, Mc, 256, 256, 2);
        }
        k_reduce<<<2*32,256,0,stream>>>(F0, PART, HW, 32);
        k_stats<<<2,256,0,stream>>>(PART, 32, HW, gbr[0], bbr[0], STATS, GAPN, 0);

        if (has_low){
            for (int p0 = 0; p0 < M; p0 += cap){
                int Mc = min(cap, M - p0);
                k_gather<<<ceildiv(Mc,64),256,0,stream>>>(X[L-1], OM, SAMP, p0, M, H, W, 2*H, 2*W, HW, W, 2, 1);
                k_gemm<<<ceildiv(Mc,128)*2,256,0,stream>>>(SAMP, BWB[1], F1 + (size_t)p0*256, nullptr, Mc, 256, 256, 2);
            }
            k_reduce<<<2*32,256,0,stream>>>(F1, PART, HW, 32);
            k_stats<<<2,256,0,stream>>>(PART, 32, HW, gbr[1], bbr[1], STATS + 64, GAPN + 512, 0);
        }
        if (has_high){
            int Hh = H/2, Wh = W/2, HWh = Hh*Wh, Mh = 2*HWh;
            for (int p0 = 0; p0 < Mh; p0 += cap){
                int Mc = min(cap, Mh - p0);
                k_gather<<<ceildiv(Mc,64),256,0,stream>>>(X[L+1], OM, SAMP, p0, Mh, Hh, Wh, Hh, Wh, HW, W, 1, 2);
                k_gemm<<<ceildiv(Mc,128)*2,256,0,stream>>>(SAMP, BWB[2], F2s + (size_t)p0*256, nullptr, Mc, 256, 256, 2);
            }
            k_reduce<<<2*32,256,0,stream>>>(F2s, PART, HWh, 32);
            k_stats<<<2,256,0,stream>>>(PART, 32, HWh, gbr[2], bbr[2], STATS + slotH*64, GAPN + slotH*512, 0);
            k_resize<<<ceildiv(M,8),256,0,stream>>>(F2s, F2r, STATS + slotH*64, gbr[2], bbr[2], H, W, Hh, Wh);
            k_reduce<<<2*32,256,0,stream>>>(F2r, PART, HW, 32);
            k_stats<<<2,256,0,stream>>>(PART, 32, HW, nullptr, nullptr, nullptr, GAPN + slotH*512, 1);
        }
        k_attn<<<2,256,0,stream>>>(GAPN, sw, sb, d1w, d1b, d2w, d2b, ABR, DYC, nbr);
        k_combine<<<2*H*ceildiv(W,16),256,0,stream>>>(
            F0, has_low ? F1 : nullptr, has_high ? F2r : nullptr,
            STATS, gbr[0], bbr[0], gbr[1], bbr[1], ABR, DYC,
            (float*)d_out + lvl_off, H, W, nbr);
        lvl_off += (size_t)M*256;
    }
}

// Round 2
// 1276.792 us; speedup vs baseline: 1.5029x; 1.5029x over previous
//
#include <hip/hip_runtime.h>
#include <hip/hip_bf16.h>
#include <stdint.h>

typedef __hip_bfloat16 bf16;
using frag_ab = __attribute__((ext_vector_type(8))) short;
using frag_cd = __attribute__((ext_vector_type(4))) float;

static __device__ __forceinline__ float hsig(float x){
    return fminf(fmaxf((x + 3.0f) * (1.0f/6.0f), 0.0f), 1.0f);
}
static inline int ceildiv(int a, int b){ return (a + b - 1) / b; }

// ---------------- weight conversion: w[O][256][3][3] fp32 -> bw[Opad][2304] bf16, K = k*256+c ----
__global__ __launch_bounds__(256) void k_convw(const float* __restrict__ w, bf16* __restrict__ bw,
                                               int Opad, int Ovalid){
    int i = blockIdx.x*256 + threadIdx.x;
    int total = Opad*2304;
    if (i >= total) return;
    int o = i / 2304, r = i - o*2304;
    int k = r >> 8, c = r & 255;
    float v = 0.f;
    if (o < Ovalid) v = w[((size_t)(o*256 + c))*9 + k];
    bw[i] = __float2bfloat16(v);
}

// ---------------- deformable / im2col gather: block = (64 pixels) x (1 tap) x (128 channels) ----
// OM layout per mid-pixel: [32] floats = {off(2k),off(2k+1) k=0..8 ; mask k=0..8 at 18+k ; pad}
__global__ __launch_bounds__(256) void k_gather(
    const float* __restrict__ X, const float* __restrict__ OM, bf16* __restrict__ S,
    int p0, int Mtot, int Ho, int Wo, int Hi, int Wi, int HmWm, int Wm, int stride, int osub)
{
    __shared__ __align__(16) int   mi[64][4];
    __shared__ __align__(16) float mw[64][4];
    __shared__ bf16 T[128*64];
    const int t = threadIdx.x;
    const int k = blockIdx.y;
    const int co0 = (int)blockIdx.z << 7;     // channel offset: 0 or 128
    const int HoWo = Ho*Wo;
    const int HiWi = Hi*Wi;
    const int pbase = p0 + blockIdx.x*64;

    if (t < 64){
        int p = pbase + t;
        bool pv = (p < Mtot);
        int pp = pv ? p : 0;
        int b = pp / HoWo; int r = pp - b*HoWo; int y = r / Wo; int x = r - y*Wo;
        float offy = 0.f, offx = 0.f, mk = 1.f;
        if (OM){
            size_t ob = ((size_t)b*HmWm + (size_t)(y*osub)*Wm + (size_t)(x*osub)) * 32;
            offy = OM[ob + 2*k]; offx = OM[ob + 2*k + 1]; mk = OM[ob + 18 + k];
        }
        if (!pv) mk = 0.f;
        int kh = k/3, kw = k - kh*3;
        float py = (float)(y*stride - 1 + kh) + offy;
        float px = (float)(x*stride - 1 + kw) + offx;
        float y0f = floorf(py), x0f = floorf(px);
        float ly = py - y0f, lx = px - x0f;
        int y0 = (int)y0f, x0 = (int)x0f;
        int y1 = y0 + 1, x1 = x0 + 1;
        float vy0 = (y0 >= 0 && y0 < Hi) ? 1.f : 0.f;
        float vy1 = (y1 >= 0 && y1 < Hi) ? 1.f : 0.f;
        float vx0 = (x0 >= 0 && x0 < Wi) ? 1.f : 0.f;
        float vx1 = (x1 >= 0 && x1 < Wi) ? 1.f : 0.f;
        float w00 = (1.f-ly)*(1.f-lx)*mk*vy0*vx0;
        float w01 = (1.f-ly)*lx*mk*vy0*vx1;
        float w10 = ly*(1.f-lx)*mk*vy1*vx0;
        float w11 = ly*lx*mk*vy1*vx1;
        int y0c = min(max(y0,0),Hi-1), y1c = min(max(y1,0),Hi-1);
        int x0c = min(max(x0,0),Wi-1), x1c = min(max(x1,0),Wi-1);
        int base = b*256*HiWi;
        mi[t][0] = base + y0c*Wi + x0c;
        mi[t][1] = base + y0c*Wi + x1c;
        mi[t][2] = base + y1c*Wi + x0c;
        mi[t][3] = base + y1c*Wi + x1c;
        mw[t][0] = w00; mw[t][1] = w01; mw[t][2] = w10; mw[t][3] = w11;
    }
    __syncthreads();

    const int pl = t & 63;
    const int c0 = (t >> 6) << 5;            // 0,32,64,96 within the 128-chunk
    int4   ii = *(const int4*)mi[pl];
    float4 ww = *(const float4*)mw[pl];
    #pragma unroll 8
    for (int j = 0; j < 32; ++j){
        int c = c0 + j;
        const float* xp = X + (size_t)(co0 + c) * HiWi;
        float v = ww.x*xp[ii.x] + ww.y*xp[ii.y] + ww.z*xp[ii.z] + ww.w*xp[ii.w];
        T[c*64 + (pl ^ ((c & 31) << 1))] = __float2bfloat16(v);
    }
    __syncthreads();

    const int cc = t & 127;
    const int r0 = (t >> 7) << 5;            // 0 or 32
    size_t rowbase = (size_t)(blockIdx.x*64) * 2304 + (size_t)k*256 + co0 + cc;
    #pragma unroll 8
    for (int i = 0; i < 32; ++i){
        int row = r0 + i;
        S[rowbase + (size_t)row*2304] = T[cc*64 + (row ^ ((cc & 31) << 1))];
    }
}

// ---------------- NT GEMM: C[M][ldc] = A[Mpad][2304] * Bw[Npad][2304]^T (+bias), bf16 MFMA ------
// 64x64 tile, 4 waves (each 32x32), BK=64, XOR-swizzled LDS.
__global__ __launch_bounds__(256) void k_gemm(
    const bf16* __restrict__ A, const bf16* __restrict__ Bw,
    float* __restrict__ C, const float* __restrict__ bias,
    int M, int ldc, int Nvalid, int nbn, int sigfrom)
{
    __shared__ __align__(16) bf16 sA[64*64];
    __shared__ __align__(16) bf16 sB[64*64];
    const int t = threadIdx.x;
    const int mb = blockIdx.x / nbn;
    const int nb = blockIdx.x - mb*nbn;
    const int m0 = mb*64, n0 = nb*64;
    const int w = t >> 6, l = t & 63;
    const int wr = w >> 1, wc = w & 1;
    const int lr = l & 15, lk = (l >> 4) * 8;
    const int K = 2304;
    frag_cd acc[2][2];
    frag_cd zero = {0.f, 0.f, 0.f, 0.f};
    for (int i = 0; i < 2; ++i) for (int j = 0; j < 2; ++j) acc[i][j] = zero;

    const int row0 = t >> 3,        kc0 = (t & 7) << 3;
    const int row1 = (256 + t) >> 3, kc1 = kc0;   // second half: rows 32..63

    for (int kt = 0; kt < 36; ++kt){
        int k0 = kt*64;
        __syncthreads();
        *(int4*)&sA[row0*64 + (kc0 ^ ((row0 & 7) << 3))] = *(const int4*)&A[(size_t)(m0 + row0)*K + (k0 + kc0)];
        *(int4*)&sB[row0*64 + (kc0 ^ ((row0 & 7) << 3))] = *(const int4*)&Bw[(size_t)(n0 + row0)*K + (k0 + kc0)];
        *(int4*)&sA[row1*64 + (kc1 ^ ((row1 & 7) << 3))] = *(const int4*)&A[(size_t)(m0 + row1)*K + (k0 + kc1)];
        *(int4*)&sB[row1*64 + (kc1 ^ ((row1 & 7) << 3))] = *(const int4*)&Bw[(size_t)(n0 + row1)*K + (k0 + kc1)];
        __syncthreads();
        #pragma unroll
        for (int kk = 0; kk < 2; ++kk){
            int col = kk*32 + lk;
            frag_ab av[2], bv[2];
            #pragma unroll
            for (int i = 0; i < 2; ++i){
                int ra = wr*32 + i*16 + lr;
                int rb = wc*32 + i*16 + lr;
                av[i] = *(const frag_ab*)&sA[ra*64 + (col ^ ((ra & 7) << 3))];
                bv[i] = *(const frag_ab*)&sB[rb*64 + (col ^ ((rb & 7) << 3))];
            }
            #pragma unroll
            for (int mi_ = 0; mi_ < 2; ++mi_)
                #pragma unroll
                for (int ni = 0; ni < 2; ++ni)
                    acc[mi_][ni] = __builtin_amdgcn_mfma_f32_16x16x32_bf16(av[mi_], bv[ni], acc[mi_][ni], 0, 0, 0);
        }
    }
    #pragma unroll
    for (int mi_ = 0; mi_ < 2; ++mi_){
        int gr0 = m0 + wr*32 + mi_*16 + ((l >> 4) << 2);
        #pragma unroll
        for (int ni = 0; ni < 2; ++ni){
            int gc = n0 + wc*32 + ni*16 + lr;
            if (gc < Nvalid){
                float bv_ = bias ? bias[gc] : 0.f;
                #pragma unroll
                for (int j = 0; j < 4; ++j){
                    int r = gr0 + j;
                    if (r < M){
                        float v = acc[mi_][ni][j] + bv_;
                        if (gc >= sigfrom) v = 1.f / (1.f + expf(-v));
                        C[(size_t)r*ldc + gc] = v;
                    }
                }
            }
        }
    }
}

// ---------------- per-(b,c) partial sums over HW (NHWC input) ----------------
__global__ __launch_bounds__(256) void k_reduce(const float* __restrict__ F, float* __restrict__ part,
                                                int HW, int nchunk){
    int b = blockIdx.x / nchunk;
    int ch = blockIdx.x - b*nchunk;
    int R = (HW + nchunk - 1) / nchunk;
    int rbeg = ch*R, rend = min(rbeg + R, HW);
    int t = threadIdx.x;
    float s1 = 0.f, s2 = 0.f;
    for (int r = rbeg; r < rend; ++r){
        float v = F[((size_t)b*HW + r)*256 + t];
        s1 += v; s2 += v*v;
    }
    size_t o = ((size_t)blockIdx.x*256 + t) * 2;
    part[o] = s1; part[o+1] = s2;
}

// ---------------- finalize GN stats + normalized GAP (mode0) or plain GAP (mode1) ---------------
__global__ __launch_bounds__(256) void k_stats(const float* __restrict__ part, int nchunk, int HW,
    const float* __restrict__ gamma, const float* __restrict__ beta,
    float* __restrict__ stats, float* __restrict__ gapn, int mode)
{
    int b = blockIdx.x, t = threadIdx.x;
    float s1 = 0.f, s2 = 0.f;
    for (int j = 0; j < nchunk; ++j){
        size_t o = ((size_t)(b*nchunk + j)*256 + t) * 2;
        s1 += part[o]; s2 += part[o+1];
    }
    float invHW = 1.0f / (float)HW;
    if (mode == 1){ gapn[b*256 + t] = s1*invHW; return; }
    float g1 = s1, g2 = s2;
    #pragma unroll
    for (int m = 8; m >= 1; m >>= 1){ g1 += __shfl_xor(g1, m, 16); g2 += __shfl_xor(g2, m, 16); }
    float mu  = g1 * invHW * (1.f/16.f);
    float var = g2 * invHW * (1.f/16.f) - mu*mu;
    float rstd = rsqrtf(var + 1e-5f);
    if ((t & 15) == 0){ int g = t >> 4; stats[(b*16+g)*2] = mu; stats[(b*16+g)*2+1] = rstd; }
    gapn[b*256 + t] = (s1*invHW - mu)*rstd*gamma[t] + beta[t];
}

// ---------------- bilinear align-corners resize of normalized high feature (NHWC) ----------------
__global__ __launch_bounds__(256) void k_resize(const float* __restrict__ Fs, float* __restrict__ Fr,
    const float* __restrict__ stats, const float* __restrict__ gamma, const float* __restrict__ beta,
    int Hm, int Wm, int Hh, int Wh)
{
    int t = threadIdx.x;
    int HWm = Hm*Wm, HWh = Hh*Wh;
    int Mm = 2*HWm;
    for (int i = 0; i < 8; ++i){
        int po = blockIdx.x*8 + i;
        if (po >= Mm) break;
        int b = po / HWm; int r = po - b*HWm; int y = r / Wm; int x = r - y*Wm;
        int ny = y*(Hh-1); int y0 = ny/(Hm-1); float wy = (float)(ny - y0*(Hm-1)) / (float)(Hm-1);
        int y1 = min(y0+1, Hh-1);
        int nx = x*(Wh-1); int x0 = nx/(Wm-1); float wx = (float)(nx - x0*(Wm-1)) / (float)(Wm-1);
        int x1 = min(x0+1, Wh-1);
        size_t basep = (size_t)b*HWh;
        float v00 = Fs[(basep + y0*Wh + x0)*256 + t];
        float v01 = Fs[(basep + y0*Wh + x1)*256 + t];
        float v10 = Fs[(basep + y1*Wh + x0)*256 + t];
        float v11 = Fs[(basep + y1*Wh + x1)*256 + t];
        float v = (1.f-wy)*((1.f-wx)*v00 + wx*v01) + wy*((1.f-wx)*v10 + wx*v11);
        int g = t >> 4;
        float mu = stats[(b*16+g)*2], rs = stats[(b*16+g)*2+1];
        Fr[(size_t)po*256 + t] = (v - mu)*rs*gamma[t] + beta[t];
    }
}

// ---------------- attention scalars + dyrelu coefficients (per batch) ----------------
__global__ __launch_bounds__(256) void k_attn(const float* __restrict__ gapn,
    const float* __restrict__ sw, const float* __restrict__ sb,
    const float* __restrict__ w1, const float* __restrict__ b1v,
    const float* __restrict__ w2, const float* __restrict__ b2v,
    float* __restrict__ abr, float* __restrict__ dyc, int nbr)
{
    int b = blockIdx.x, t = threadIdx.x;
    const int B = gridDim.x;
    __shared__ float red[256];
    __shared__ float asl[3];
    __shared__ float gm[256];
    __shared__ float hh[64];
    for (int br = 0; br < nbr; ++br){
        red[t] = gapn[((size_t)br*B + b)*256 + t] * sw[t];
        __syncthreads();
        for (int s = 128; s > 0; s >>= 1){ if (t < s) red[t] += red[t+s]; __syncthreads(); }
        if (t == 0) asl[br] = hsig(fmaxf(red[0] + sb[0], 0.f));
        __syncthreads();
    }
    float gmv = 0.f;
    for (int br = 0; br < nbr; ++br) gmv += asl[br]*gapn[((size_t)br*B + b)*256 + t];
    gmv /= (float)nbr;
    gm[t] = gmv;
    __syncthreads();
    if (t < 64){
        float h = b1v[t];
        for (int c = 0; c < 256; ++c) h += w1[t*256 + c]*gm[c];
        hh[t] = fmaxf(h, 0.f);
    }
    __syncthreads();
    float co[4];
    #pragma unroll
    for (int q = 0; q < 4; ++q){
        int o = q*256 + t;
        float s = b2v[o];
        for (int kk = 0; kk < 64; ++kk) s += w2[o*64 + kk]*hh[kk];
        co[q] = hsig(s);
    }
    dyc[((size_t)b*256 + t)*4 + 0] = (co[0] - 0.5f)*2.f + 1.f;
    dyc[((size_t)b*256 + t)*4 + 1] =  co[1] - 0.5f;
    dyc[((size_t)b*256 + t)*4 + 2] = (co[2] - 0.5f)*2.f;
    dyc[((size_t)b*256 + t)*4 + 3] =  co[3] - 0.5f;
    if (t < nbr) abr[b*3 + t] = asl[t];
}

// ---------------- combine branches + dyrelu, NHWC -> NCHW output ----------------
__global__ __launch_bounds__(256) void k_combine(
    const float* __restrict__ f0, const float* __restrict__ f1, const float* __restrict__ f2n,
    const float* __restrict__ stats,
    const float* __restrict__ g0, const float* __restrict__ b0,
    const float* __restrict__ gl, const float* __restrict__ bl,
    const float* __restrict__ abr, const float* __restrict__ dyc,
    float* __restrict__ outp, int H, int W, int nbr)
{
    __shared__ float TL[256*17];
    int t = threadIdx.x;
    int nchx = (W + 15) >> 4;
    int bid = blockIdx.x;
    int cx = bid % nchx; int rem = bid / nchx;
    int y = rem % H; int b = rem / H;
    float a0 = abr[b*3 + 0];
    float alow = f1 ? abr[b*3 + 1] : 0.f;
    float ahigh = abr[b*3 + (nbr-1)];
    float inv = 1.f / (float)nbr;
    int g = t >> 4;
    float mu0 = stats[b*32 + g*2],       rs0 = stats[b*32 + g*2 + 1];
    float mu1 = f1 ? stats[64 + b*32 + g*2] : 0.f;
    float rs1 = f1 ? stats[64 + b*32 + g*2 + 1] : 0.f;
    float4 dc = *(const float4*)&dyc[((size_t)b*256 + t)*4];
    size_t HW = (size_t)H*W;
    for (int i = 0; i < 16; ++i){
        int x = (cx << 4) + i;
        if (x < W){
            size_t row = (size_t)b*HW + (size_t)y*W + x;
            float v = a0 * ((f0[row*256 + t] - mu0)*rs0*g0[t] + b0[t]);
            if (f1)  v += alow  * ((f1[row*256 + t] - mu1)*rs1*gl[t] + bl[t]);
            if (f2n) v += ahigh * f2n[row*256 + t];
            v *= inv;
            TL[t*17 + i] = fmaxf(v*dc.x + dc.y, v*dc.z + dc.w);
        }
    }
    __syncthreads();
    int px = t & 15, cw = t >> 4;
    for (int cb = 0; cb < 16; ++cb){
        int c = cb*16 + cw;
        int x = (cx << 4) + px;
        if (x < W) outp[((size_t)(b*256 + c)*H + y)*W + x] = TL[c*17 + px];
    }
}

extern "C" void kernel_launch(void* const* d_in, const int* in_sizes, int n_in,
                              void* d_out, int out_size, void* d_ws, size_t ws_size,
                              hipStream_t stream)
{
    (void)in_sizes; (void)n_in; (void)out_size;
    const float* X[3]   = {(const float*)d_in[0], (const float*)d_in[1], (const float*)d_in[2]};
    const float* off_w  = (const float*)d_in[3];
    const float* off_b  = (const float*)d_in[4];
    const float* wbr[3] = {(const float*)d_in[5], (const float*)d_in[8], (const float*)d_in[11]};
    const float* gbr[3] = {(const float*)d_in[6], (const float*)d_in[9], (const float*)d_in[12]};
    const float* bbr[3] = {(const float*)d_in[7], (const float*)d_in[10], (const float*)d_in[13]};
    const float* sw  = (const float*)d_in[14];
    const float* sb  = (const float*)d_in[15];
    const float* d1w = (const float*)d_in[16];
    const float* d1b = (const float*)d_in[17];
    const float* d2w = (const float*)d_in[18];
    const float* d2b = (const float*)d_in[19];

    const int Hs[3] = {80, 40, 20};
    const int NCH = 128;           // reduce chunks
    uint8_t* base = (uint8_t*)d_ws;
    size_t off = 0;
    auto alloc = [&](size_t bytes)->void*{
        off = (off + 255) & ~(size_t)255;
        void* p = base + off; off += bytes; return p;
    };
    bf16* BWO = (bf16*)alloc((size_t)64*2304*2);
    bf16* BWB[3];
    for (int i = 0; i < 3; ++i) BWB[i] = (bf16*)alloc((size_t)256*2304*2);
    float* OM   = (float*)alloc((size_t)12800*32*4);
    float* F0   = (float*)alloc((size_t)12800*256*4);
    float* F1   = (float*)alloc((size_t)3200*256*4);
    float* F2s  = (float*)alloc((size_t)3200*256*4);
    float* F2r  = (float*)alloc((size_t)12800*256*4);
    float* PART = (float*)alloc((size_t)2*NCH*256*2*4);
    float* GAPN = (float*)alloc((size_t)3*2*256*4);
    float* STATS= (float*)alloc((size_t)3*2*16*2*4);
    float* ABR  = (float*)alloc((size_t)2*3*4 + 32);
    float* DYC  = (float*)alloc((size_t)2*256*4*4);
    off = (off + 255) & ~(size_t)255;
    size_t remain = (ws_size > off) ? ws_size - off : 0;
    int cap = (int)(remain / 4608);
    cap &= ~127;
    if (cap > 12800) cap = 12800;
    if (cap < 128) cap = 128;
    bf16* SAMP = (bf16*)(base + off);

    k_convw<<<ceildiv(64*2304,256),256,0,stream>>>(off_w, BWO, 64, 27);
    for (int i = 0; i < 3; ++i)
        k_convw<<<ceildiv(256*2304,256),256,0,stream>>>(wbr[i], BWB[i], 256, 256);

    const int BIG = 1 << 30;
    size_t lvl_off = 0;
    for (int L = 0; L < 3; ++L){
        int H = Hs[L], W = Hs[L];
        int HW = H*W, M = 2*HW;
        bool has_low = (L > 0), has_high = (L < 2);
        int nbr = 1 + (has_low ? 1 : 0) + (has_high ? 1 : 0);
        int slotH = nbr - 1;

        // offset conv (im2col + GEMM N=27, sigmoid fused on mask cols) -> OM
        for (int p0 = 0; p0 < M; p0 += cap){
            int Mc = min(cap, M - p0);
            k_gather<<<dim3(ceildiv(Mc,64),9,2),256,0,stream>>>(X[L], nullptr, SAMP, p0, M, H, W, H, W, HW, W, 1, 1);
            k_gemm<<<ceildiv(Mc,64),256,0,stream>>>(SAMP, BWO, OM + (size_t)p0*32, off_b, Mc, 32, 27, 1, 18);
        }

        // mid branch (slot 0)
        for (int p0 = 0; p0 < M; p0 += cap){
            int Mc = min(cap, M - p0);
            k_gather<<<dim3(ceildiv(Mc,64),9,2),256,0,stream>>>(X[L], OM, SAMP, p0, M, H, W, H, W, HW, W, 1, 1);
            k_gemm<<<ceildiv(Mc,64)*4,256,0,stream>>>(SAMP, BWB[0], F0 + (size_t)p0*256, nullptr, Mc, 256, 256, 4, BIG);
        }
        k_reduce<<<2*NCH,256,0,stream>>>(F0, PART, HW, NCH);
        k_stats<<<2,256,0,stream>>>(PART, NCH, HW, gbr[0], bbr[0], STATS, GAPN, 0);

        if (has_low){
            for (int p0 = 0; p0 < M; p0 += cap){
                int Mc = min(cap, M - p0);
                k_gather<<<dim3(ceildiv(Mc,64),9,2),256,0,stream>>>(X[L-1], OM, SAMP, p0, M, H, W, 2*H, 2*W, HW, W, 2, 1);
                k_gemm<<<ceildiv(Mc,64)*4,256,0,stream>>>(SAMP, BWB[1], F1 + (size_t)p0*256, nullptr, Mc, 256, 256, 4, BIG);
            }
            k_reduce<<<2*NCH,256,0,stream>>>(F1, PART, HW, NCH);
            k_stats<<<2,256,0,stream>>>(PART, NCH, HW, gbr[1], bbr[1], STATS + 64, GAPN + 512, 0);
        }
        if (has_high){
            int Hh = H/2, Wh = W/2, HWh = Hh*Wh, Mh = 2*HWh;
            for (int p0 = 0; p0 < Mh; p0 += cap){
                int Mc = min(cap, Mh - p0);
                k_gather<<<dim3(ceildiv(Mc,64),9,2),256,0,stream>>>(X[L+1], OM, SAMP, p0, Mh, Hh, Wh, Hh, Wh, HW, W, 1, 2);
                k_gemm<<<ceildiv(Mc,64)*4,256,0,stream>>>(SAMP, BWB[2], F2s + (size_t)p0*256, nullptr, Mc, 256, 256, 4, BIG);
            }
            k_reduce<<<2*NCH,256,0,stream>>>(F2s, PART, HWh, NCH);
            k_stats<<<2,256,0,stream>>>(PART, NCH, HWh, gbr[2], bbr[2], STATS + slotH*64, GAPN + slotH*512, 0);
            k_resize<<<ceildiv(M,8),256,0,stream>>>(F2s, F2r, STATS + slotH*64, gbr[2], bbr[2], H, W, Hh, Wh);
            k_reduce<<<2*NCH,256,0,stream>>>(F2r, PART, HW, NCH);
            k_stats<<<2,256,0,stream>>>(PART, NCH, HW, nullptr, nullptr, nullptr, GAPN + slotH*512, 1);
        }
        k_attn<<<2,256,0,stream>>>(GAPN, sw, sb, d1w, d1b, d2w, d2b, ABR, DYC, nbr);
        k_combine<<<2*H*ceildiv(W,16),256,0,stream>>>(
            F0, has_low ? F1 : nullptr, has_high ? F2r : nullptr,
            STATS, gbr[0], bbr[0], gbr[1], bbr[1], ABR, DYC,
            (float*)d_out + lvl_off, H, W, nbr);
        lvl_off += (size_t)M*256;
    }
}